// Round 9
// baseline (23.960 us; speedup 1.0000x reference)
//
#include <hip/hip_runtime.h>
#include <cstdint>
#include <cstddef>
#include <algorithm>

// ---------------- problem constants ----------------
#define NROW 16      // only bn rows 0..15 feed the outputs (n=16)
#define CTOT 384
#define HW   1024    // 32*32
#define KSEL 20
#define PSEL 96
#define NREM 76      // P - K
#define NUNSEL 1004  // HW - K
#define NSL  16      // 2-row slices per image

typedef unsigned long long u64;

struct Perm76 { int p[NREM]; };

// ---------------- kernel A: full-channel-sum conv per 2-row slice (no partials) ----------------
// grid = NROW*NSL (256) blocks x 512 threads = 1 block/CU. Block (r,sl) computes the final
// score for rows 2sl..2sl+1 of image r by summing all 384 channels in one pass.
__global__ __launch_bounds__(512) void pv_conv(
    const float* __restrict__ feat, const float* __restrict__ dw_w,
    const float* __restrict__ pw_w, float* __restrict__ score)
{
  __shared__ float wlds[CTOT * 12];       // fused weights, padded to 12/ch (b128-aligned)
  __shared__ float red[64][68];           // per-lane-group partials, padded stride
  __shared__ float qred[8][64];
  const int t  = threadIdx.x;
  const int r  = blockIdx.x >> 4;
  const int sl = blockIdx.x & 15;

  // stage fused weights (dw * pw), padded stride 12
  for (int e = t; e < CTOT * 9; e += 512) {
    const int ch = e / 9, k = e - 9 * ch;
    wlds[ch * 12 + k] = dw_w[e] * pw_w[ch];
  }

  const int c = t & 7;            // col group: cols 4c..4c+3
  const int g = t >> 3;           // channel lane-group 0..63
  const int y0 = 2 * sl;
  const float* base = feat + (size_t)r * CTOT * HW;
  __syncthreads();

  float acc0[4] = {0.f, 0.f, 0.f, 0.f};
  float acc1[4] = {0.f, 0.f, 0.f, 0.f};

  for (int i = 0; i < 6; ++i) {           // channels g, g+64, ..., g+320
    const int ch = g + 64 * i;
    const float* pb = base + (size_t)ch * HW + 4 * c;
    float4 f[4];
    #pragma unroll
    for (int m = 0; m < 4; ++m) {         // input rows y0-1 .. y0+2 (clamped)
      int row = y0 - 1 + m;
      row = row < 0 ? 0 : (row > 31 ? 31 : row);
      f[m] = *reinterpret_cast<const float4*>(pb + row * 32);
    }
    if (sl == 0)       { f[0].x = 0.f; f[0].y = 0.f; f[0].z = 0.f; f[0].w = 0.f; }
    if (sl == NSL - 1) { f[3].x = 0.f; f[3].y = 0.f; f[3].z = 0.f; f[3].w = 0.f; }

    float L[4], R[4];
    #pragma unroll
    for (int m = 0; m < 4; ++m) {
      L[m] = __shfl_up(f[m].w, 1, 8);     // col 4c-1 from lane-1 (8-lane groups)
      R[m] = __shfl_down(f[m].x, 1, 8);   // col 4c+4 from lane+1
    }
    if (c == 0) { L[0] = 0.f; L[1] = 0.f; L[2] = 0.f; L[3] = 0.f; }
    if (c == 7) { R[0] = 0.f; R[1] = 0.f; R[2] = 0.f; R[3] = 0.f; }

    const float4 wa = *reinterpret_cast<const float4*>(&wlds[ch * 12]);
    const float4 wb = *reinterpret_cast<const float4*>(&wlds[ch * 12 + 4]);
    const float  w8 = wlds[ch * 12 + 8];
    const float w9[9] = { wa.x, wa.y, wa.z, wa.w, wb.x, wb.y, wb.z, wb.w, w8 };

    #pragma unroll
    for (int d = 0; d < 3; ++d) {
      {   // output row y0 uses input row m = d
        const float a = L[d], b0 = f[d].x, b1 = f[d].y, b2 = f[d].z, b3 = f[d].w, e = R[d];
        acc0[0] += a  * w9[3*d] + b0 * w9[3*d+1] + b1 * w9[3*d+2];
        acc0[1] += b0 * w9[3*d] + b1 * w9[3*d+1] + b2 * w9[3*d+2];
        acc0[2] += b1 * w9[3*d] + b2 * w9[3*d+1] + b3 * w9[3*d+2];
        acc0[3] += b2 * w9[3*d] + b3 * w9[3*d+1] + e  * w9[3*d+2];
      }
      {   // output row y0+1 uses input row m = d+1
        const float a = L[d+1], b0 = f[d+1].x, b1 = f[d+1].y, b2 = f[d+1].z, b3 = f[d+1].w, e = R[d+1];
        acc1[0] += a  * w9[3*d] + b0 * w9[3*d+1] + b1 * w9[3*d+2];
        acc1[1] += b0 * w9[3*d] + b1 * w9[3*d+1] + b2 * w9[3*d+2];
        acc1[2] += b1 * w9[3*d] + b2 * w9[3*d+1] + b3 * w9[3*d+2];
        acc1[3] += b2 * w9[3*d] + b3 * w9[3*d+1] + e  * w9[3*d+2];
      }
    }
  }

  // two-stage cross-group reduction (64 lane-groups -> 1)
  *reinterpret_cast<float4*>(&red[g][4 * c])      = make_float4(acc0[0], acc0[1], acc0[2], acc0[3]);
  *reinterpret_cast<float4*>(&red[g][32 + 4 * c]) = make_float4(acc1[0], acc1[1], acc1[2], acc1[3]);
  __syncthreads();
  {
    const int q = t >> 6, p = t & 63;
    float s = 0.f;
    #pragma unroll
    for (int gg = 0; gg < 8; ++gg) s += red[8 * q + gg][p];
    qred[q][p] = s;
  }
  __syncthreads();
  if (t < 64) {
    float s = 0.f;
    #pragma unroll
    for (int q = 0; q < 8; ++q) s += qred[q][t];
    score[(size_t)r * HW + sl * 64 + t] = s;    // px = (2sl + j)*32 + col
  }
}

// ---------------- kernel B: slice top-20 + global top-20 + selection + emit (proven R8 logic) ----------------
// grid = NROW blocks, 256 threads. Output: x_out (16*96) then y_out (16*96), int32.
__global__ __launch_bounds__(256) void pv_select(
    const float* __restrict__ score, int* __restrict__ out, Perm76 perm)
{
  __shared__ u64 keysh[HW];                  // 8 KB
  __shared__ u64 cand[8 * KSEL];             // 160 candidates
  __shared__ int votes[KSEL];
  __shared__ int maskv[HW];
  __shared__ int wsumS[4];
  __shared__ int unsel[NUNSEL];

  const int r = blockIdx.x;
  const int t = threadIdx.x;
  const int lane = t & 63, wv = t >> 6;

  // load scores -> monotone sortable keys (larger score wins; tie -> smaller index)
  const float4 sv4 = reinterpret_cast<const float4*>(score + (size_t)r * HW)[t];
  const float sv[4] = { sv4.x, sv4.y, sv4.z, sv4.w };
  u64 key[4];
  #pragma unroll
  for (int q = 0; q < 4; ++q) {
    const int i = 4 * t + q;
    const uint32_t bb = __float_as_uint(sv[q]);
    const uint32_t mm = (bb & 0x80000000u) ? ~bb : (bb | 0x80000000u);
    key[q] = ((u64)mm << 32) | (uint32_t)(1023 - i);
    keysh[i] = key[q];
  }
  maskv[t] = 0; maskv[t + 256] = 0; maskv[t + 512] = 0; maskv[t + 768] = 0;
  __syncthreads();

  // slice-local rank (128-px slices; broadcast-friendly LDS reads)
  {
    const u64* sk = &keysh[(t >> 5) * 128];
    int rk0 = 0, rk1 = 0, rk2 = 0, rk3 = 0;
    for (int j = 0; j < 128; ++j) {
      const u64 kj = sk[j];
      rk0 += (kj > key[0]); rk1 += (kj > key[1]);
      rk2 += (kj > key[2]); rk3 += (kj > key[3]);
    }
    const int rk[4] = { rk0, rk1, rk2, rk3 };
    #pragma unroll
    for (int q = 0; q < 4; ++q)
      if (rk[q] < KSEL) cand[(t >> 5) * KSEL + rk[q]] = key[q];
  }
  __syncthreads();

  // exact global top-20 (union of slice top-20s contains it)
  if (t < 8 * KSEL) {
    const u64 my = cand[t];
    int rank = 0;
    for (int j = 0; j < 8 * KSEL; ++j) rank += (cand[j] > my);
    if (rank < KSEL) votes[rank] = 1023 - (int)(my & 1023ull);
  }
  __syncthreads();

  // selected coords + mask
  if (t < KSEL) {
    const int idx = votes[t];
    maskv[idx] = 1;
    int xx = idx & 31, yy = idx >> 5;
    if (xx < 1) xx = 1;                      // clip(.,1,31); upper bound can't trigger
    if (yy < 1) yy = 1;
    out[r * PSEL + t]               = xx;
    out[NROW * PSEL + r * PSEL + t] = yy;
  }
  __syncthreads();

  // unselected indices ascending via shfl prefix over !mask
  int cnt = 0;
  #pragma unroll
  for (int j = 0; j < 4; ++j) cnt += (maskv[t * 4 + j] == 0);
  int inc = cnt;
  #pragma unroll
  for (int dd = 1; dd < 64; dd <<= 1) {
    const int o = __shfl_up(inc, dd);
    if (lane >= dd) inc += o;
  }
  if (lane == 63) wsumS[wv] = inc;
  __syncthreads();
  int basep = 0;
  for (int i = 0; i < 4; ++i) if (i < wv) basep += wsumS[i];
  int pos = basep + inc - cnt;               // exclusive prefix
  #pragma unroll
  for (int j = 0; j < 4; ++j) {
    const int i = t * 4 + j;
    if (!maskv[i]) unsel[pos++] = i;
  }
  __syncthreads();

  // random remaining via fixed permutation
  if (t < NREM) {
    const int u = unsel[perm.p[t]];
    int xx = u & 31, yy = u >> 5;
    if (xx < 1) xx = 1;
    if (yy < 1) yy = 1;
    out[r * PSEL + KSEL + t]               = xx;
    out[NROW * PSEL + r * PSEL + KSEL + t] = yy;
  }
}

// ---------------- host: JAX threefry2x32 (partitionable) ----------------
static inline uint32_t rotl32(uint32_t v, uint32_t n) { return (v << n) | (v >> (32 - n)); }

static void tf2x32(uint32_t k0, uint32_t k1, uint32_t x0, uint32_t x1,
                   uint32_t* o0, uint32_t* o1)
{
  const uint32_t ks[3] = { k0, k1, k0 ^ k1 ^ 0x1BD11BDAu };
  static const uint32_t rot[2][4] = { {13, 15, 26, 6}, {17, 29, 16, 24} };
  x0 += ks[0]; x1 += ks[1];
  for (int i = 0; i < 5; ++i) {
    const uint32_t* rr = rot[i & 1];
    for (int j = 0; j < 4; ++j) { x0 += x1; x1 = rotl32(x1, rr[j]); x1 ^= x0; }
    x0 += ks[(i + 1) % 3];
    x1 += ks[(i + 2) % 3] + (uint32_t)(i + 1);
  }
  *o0 = x0; *o1 = x1;
}

// perm = jax.random.permutation(jax.random.key(42), 1004)[:76]  (threefry_partitionable)
static void compute_perm(int* perm_out)
{
  uint32_t bits[NUNSEL];
  uint32_t sk0, sk1;
  { uint32_t o0, o1; tf2x32(0u, 42u, 0u, 1u, &o0, &o1); sk0 = o0; sk1 = o1; }
  for (int i = 0; i < NUNSEL; ++i) {
    uint32_t o0, o1; tf2x32(sk0, sk1, 0u, (uint32_t)i, &o0, &o1);
    bits[i] = o0 ^ o1;
  }
  int idx[NUNSEL];
  for (int i = 0; i < NUNSEL; ++i) idx[i] = i;
  std::stable_sort(idx, idx + NUNSEL, [&](int a, int b) { return bits[a] < bits[b]; });
  for (int j = 0; j < NREM; ++j) perm_out[j] = idx[j];
}

extern "C" void kernel_launch(void* const* d_in, const int* in_sizes, int n_in,
                              void* d_out, int out_size, void* d_ws, size_t ws_size,
                              hipStream_t stream)
{
  (void)in_sizes; (void)n_in; (void)out_size; (void)ws_size;
  const float* feat = (const float*)d_in[0];
  const float* dw_w = (const float*)d_in[1];
  // d_in[2] = dw_b (zeros; constant shift, ordering-irrelevant)
  const float* pw_w = (const float*)d_in[3];
  // d_in[4] = pw_b (constant shift, ordering-irrelevant)
  int*   out   = (int*)d_out;
  float* score = (float*)d_ws;               // NROW*HW f32 = 64 KB, fully rewritten

  Perm76 perm;
  compute_perm(perm.p);                      // deterministic host compute, kernel-arg baked

  pv_conv<<<NROW * NSL, 512, 0, stream>>>(feat, dw_w, pw_w, score);
  pv_select<<<NROW, 256, 0, stream>>>(score, out, perm);
}

// Round 10
// 20.377 us; speedup vs baseline: 1.1758x; 1.1758x over previous
//
#include <hip/hip_runtime.h>
#include <cstdint>
#include <cstddef>
#include <algorithm>

// ---------------- problem constants ----------------
#define NROW 16      // only bn rows 0..15 feed the outputs (n=16)
#define CTOT 384
#define HW   1024    // 32*32
#define KSEL 20
#define PSEL 96
#define NREM 76      // P - K
#define NUNSEL 1004  // HW - K

#define CPB   8                  // channels per block = 1 per wave (kernel A)
#define SPLIT (CTOT / CPB)       // 48

typedef unsigned long long u64;

struct Perm76 { int p[NREM]; };

// ---------------- conv job: 4x4 tile of one channel, rows in registers, halos via shfl ----------------
__device__ __forceinline__ void conv_job(const float4* f6, const float* w9,
                                         int b, int c, float acc[4][4])
{
  #pragma unroll
  for (int m = 0; m < 6; ++m) {
    float4 f = f6[m];
    const bool dead = (b == 0 && m == 0) || (b == 7 && m == 5);   // out-of-plane row
    if (dead) { f.x = 0.f; f.y = 0.f; f.z = 0.f; f.w = 0.f; }
    float L = __shfl_up(f.w, 1);     // col 4c-1 from lane-1 (row-mask inherited)
    float R = __shfl_down(f.x, 1);   // col 4c+4 from lane+1
    if (c == 0) L = 0.f;
    if (c == 7) R = 0.f;
    const float c6[6] = { L, f.x, f.y, f.z, f.w, R };
    #pragma unroll
    for (int j = 0; j < 4; ++j) {
      const int d = m - j;           // kernel row
      if (d >= 0 && d < 3) {
        #pragma unroll
        for (int k = 0; k < 4; ++k)
          acc[j][k] += c6[k]     * w9[3 * d]
                     + c6[k + 1] * w9[3 * d + 1]
                     + c6[k + 2] * w9[3 * d + 2];
      }
    }
  }
}

// ---------------- kernel A: shuffle-conv, 1 channel/wave, 8 waves/block -> partial planes ----------------
// grid = NROW*SPLIT (768) blocks x 512 threads = 3 blocks/CU -> 24 waves/CU. Block (r,s):
// wave w owns channel s*8+w. Cross-wave sum via 32 KB LDS, float4 partial store.
__global__ __launch_bounds__(512) void pv_conv(
    const float* __restrict__ feat, const float* __restrict__ dw_w,
    const float* __restrict__ pw_w, float* __restrict__ partial)
{
  __shared__ float red[8][HW];                  // 32 KB
  const int t = threadIdx.x;
  const int w = t >> 6, lane = t & 63;
  const int b = lane >> 3, c = lane & 7;        // 4x4 tile at rows 4b.., cols 4c..
  const int r = blockIdx.x & (NROW - 1);
  const int s = blockIdx.x >> 4;
  const int ch = s * CPB + w;
  const float* base = feat + ((size_t)r * CTOT + ch) * HW;

  // issue all 6 row-loads first (coalesced float4; halo rows dedup in L1/L2)
  float4 f[6];
  #pragma unroll
  for (int m = 0; m < 6; ++m) {
    const int row = 4 * b + m - 1;
    const int rc = row < 0 ? 0 : (row > 31 ? 31 : row);
    f[m] = *reinterpret_cast<const float4*>(base + rc * 32 + 4 * c);
  }

  // fused weights (wave-uniform addresses -> scalar loads)
  float w9[9];
  {
    const float pw = pw_w[ch];
    #pragma unroll
    for (int i = 0; i < 9; ++i) w9[i] = dw_w[ch * 9 + i] * pw;
  }

  float acc[4][4];
  #pragma unroll
  for (int j = 0; j < 4; ++j)
    #pragma unroll
    for (int k = 0; k < 4; ++k) acc[j][k] = 0.f;

  conv_job(f, w9, b, c, acc);

  // park per-wave channel plane (disjoint buffers; conflict-free float4 traffic)
  #pragma unroll
  for (int j = 0; j < 4; ++j)
    *reinterpret_cast<float4*>(&red[w][(4 * b + j) * 32 + 4 * c]) =
        make_float4(acc[j][0], acc[j][1], acc[j][2], acc[j][3]);
  __syncthreads();

  if (t < 256) {
    float4 sum = make_float4(0.f, 0.f, 0.f, 0.f);
    #pragma unroll
    for (int g = 0; g < 8; ++g) {
      const float4 v = *reinterpret_cast<const float4*>(&red[g][4 * t]);
      sum.x += v.x; sum.y += v.y; sum.z += v.z; sum.w += v.w;
    }
    *reinterpret_cast<float4*>(partial + ((size_t)(r * SPLIT + s)) * HW + 4 * t) = sum;
  }
}

// ---------------- kernel B: reduce 48 planes + slice top-20 + global top-20 + emit ----------------
// grid = NROW blocks x 512 threads. Select phases run at tt = t&255 with both thread-halves
// duplicating identical work (benign same-value writes) so no guarded __syncthreads.
// Output: x_out (16*96) then y_out (16*96), int32.
__global__ __launch_bounds__(512) void pv_select(
    const float* __restrict__ partial, int* __restrict__ out, Perm76 perm)
{
  __shared__ float redB[2][HW];              // 8 KB
  __shared__ u64 keysh[HW];                  // 8 KB
  __shared__ u64 cand[8 * KSEL];             // 160 candidates
  __shared__ int votes[KSEL];
  __shared__ int maskv[HW];
  __shared__ int wsumS[4];
  __shared__ int unsel[NUNSEL];

  const int r = blockIdx.x;
  const int t = threadIdx.x;
  const int tt = t & 255, h = t >> 8;
  const int lane = t & 63;
  const int wv = tt >> 6;

  // phase 1: half h reduces planes 24h..24h+23 at float4 slot tt (6-deep MLP, L2-resident)
  {
    const float* bp = partial + ((size_t)(r * SPLIT + 24 * h)) * HW + 4 * tt;
    float4 A[6];
    #pragma unroll
    for (int i = 0; i < 6; ++i) A[i] = make_float4(0.f, 0.f, 0.f, 0.f);
    #pragma unroll
    for (int s = 0; s < 24; s += 6) {
      #pragma unroll
      for (int i = 0; i < 6; ++i) {
        const float4 v = *reinterpret_cast<const float4*>(bp + (size_t)(s + i) * HW);
        A[i].x += v.x; A[i].y += v.y; A[i].z += v.z; A[i].w += v.w;
      }
    }
    #pragma unroll
    for (int i = 1; i < 6; ++i) {
      A[0].x += A[i].x; A[0].y += A[i].y; A[0].z += A[i].z; A[0].w += A[i].w;
    }
    *reinterpret_cast<float4*>(&redB[h][4 * tt]) = A[0];
  }
  maskv[tt] = 0; maskv[tt + 256] = 0; maskv[tt + 512] = 0; maskv[tt + 768] = 0;
  __syncthreads();

  // phase 2: monotone sortable keys (larger score wins; tie -> smaller index)
  u64 key[4];
  {
    const float4 a = *reinterpret_cast<const float4*>(&redB[0][4 * tt]);
    const float4 b = *reinterpret_cast<const float4*>(&redB[1][4 * tt]);
    const float sv[4] = { a.x + b.x, a.y + b.y, a.z + b.z, a.w + b.w };
    #pragma unroll
    for (int q = 0; q < 4; ++q) {
      const int i = 4 * tt + q;
      const uint32_t bb = __float_as_uint(sv[q]);
      const uint32_t mm = (bb & 0x80000000u) ? ~bb : (bb | 0x80000000u);
      key[q] = ((u64)mm << 32) | (uint32_t)(1023 - i);
      keysh[i] = key[q];
    }
  }
  __syncthreads();

  // phase 3: slice-local rank (128-px slices; broadcast-friendly LDS reads)
  {
    const u64* sk = &keysh[(tt >> 5) * 128];
    int rk0 = 0, rk1 = 0, rk2 = 0, rk3 = 0;
    for (int j = 0; j < 128; ++j) {
      const u64 kj = sk[j];
      rk0 += (kj > key[0]); rk1 += (kj > key[1]);
      rk2 += (kj > key[2]); rk3 += (kj > key[3]);
    }
    const int rk[4] = { rk0, rk1, rk2, rk3 };
    #pragma unroll
    for (int q = 0; q < 4; ++q)
      if (rk[q] < KSEL) cand[(tt >> 5) * KSEL + rk[q]] = key[q];
  }
  __syncthreads();

  // phase 4: exact global top-20 (union of slice top-20s contains it)
  if (tt < 8 * KSEL) {
    const u64 my = cand[tt];
    int rank = 0;
    for (int j = 0; j < 8 * KSEL; ++j) rank += (cand[j] > my);
    if (rank < KSEL) votes[rank] = 1023 - (int)(my & 1023ull);
  }
  __syncthreads();

  // selected coords + mask
  if (tt < KSEL) {
    const int idx = votes[tt];
    maskv[idx] = 1;
    int xx = idx & 31, yy = idx >> 5;
    if (xx < 1) xx = 1;                      // clip(.,1,31); upper bound can't trigger
    if (yy < 1) yy = 1;
    out[r * PSEL + tt]               = xx;
    out[NROW * PSEL + r * PSEL + tt] = yy;
  }
  __syncthreads();

  // unselected indices ascending via shfl prefix over !mask (halves duplicate identically)
  int cnt = 0;
  #pragma unroll
  for (int j = 0; j < 4; ++j) cnt += (maskv[tt * 4 + j] == 0);
  int inc = cnt;
  #pragma unroll
  for (int dd = 1; dd < 64; dd <<= 1) {
    const int o = __shfl_up(inc, dd);
    if (lane >= dd) inc += o;
  }
  if (lane == 63) wsumS[wv] = inc;
  __syncthreads();
  int basep = 0;
  for (int i = 0; i < 4; ++i) if (i < wv) basep += wsumS[i];
  int pos = basep + inc - cnt;               // exclusive prefix
  #pragma unroll
  for (int j = 0; j < 4; ++j) {
    const int i = tt * 4 + j;
    if (!maskv[i]) unsel[pos++] = i;
  }
  __syncthreads();

  // random remaining via fixed permutation
  if (tt < NREM) {
    const int u = unsel[perm.p[tt]];
    int xx = u & 31, yy = u >> 5;
    if (xx < 1) xx = 1;
    if (yy < 1) yy = 1;
    out[r * PSEL + KSEL + tt]               = xx;
    out[NROW * PSEL + r * PSEL + KSEL + tt] = yy;
  }
}

// ---------------- host: JAX threefry2x32 (partitionable) ----------------
static inline uint32_t rotl32(uint32_t v, uint32_t n) { return (v << n) | (v >> (32 - n)); }

static void tf2x32(uint32_t k0, uint32_t k1, uint32_t x0, uint32_t x1,
                   uint32_t* o0, uint32_t* o1)
{
  const uint32_t ks[3] = { k0, k1, k0 ^ k1 ^ 0x1BD11BDAu };
  static const uint32_t rot[2][4] = { {13, 15, 26, 6}, {17, 29, 16, 24} };
  x0 += ks[0]; x1 += ks[1];
  for (int i = 0; i < 5; ++i) {
    const uint32_t* rr = rot[i & 1];
    for (int j = 0; j < 4; ++j) { x0 += x1; x1 = rotl32(x1, rr[j]); x1 ^= x0; }
    x0 += ks[(i + 1) % 3];
    x1 += ks[(i + 2) % 3] + (uint32_t)(i + 1);
  }
  *o0 = x0; *o1 = x1;
}

// perm = jax.random.permutation(jax.random.key(42), 1004)[:76]  (threefry_partitionable)
static void compute_perm(int* perm_out)
{
  uint32_t bits[NUNSEL];
  uint32_t sk0, sk1;
  { uint32_t o0, o1; tf2x32(0u, 42u, 0u, 1u, &o0, &o1); sk0 = o0; sk1 = o1; }
  for (int i = 0; i < NUNSEL; ++i) {
    uint32_t o0, o1; tf2x32(sk0, sk1, 0u, (uint32_t)i, &o0, &o1);
    bits[i] = o0 ^ o1;
  }
  int idx[NUNSEL];
  for (int i = 0; i < NUNSEL; ++i) idx[i] = i;
  std::stable_sort(idx, idx + NUNSEL, [&](int a, int b) { return bits[a] < bits[b]; });
  for (int j = 0; j < NREM; ++j) perm_out[j] = idx[j];
}

extern "C" void kernel_launch(void* const* d_in, const int* in_sizes, int n_in,
                              void* d_out, int out_size, void* d_ws, size_t ws_size,
                              hipStream_t stream)
{
  (void)in_sizes; (void)n_in; (void)out_size; (void)ws_size;
  const float* feat = (const float*)d_in[0];
  const float* dw_w = (const float*)d_in[1];
  // d_in[2] = dw_b (zeros; constant shift, ordering-irrelevant)
  const float* pw_w = (const float*)d_in[3];
  // d_in[4] = pw_b (constant shift, ordering-irrelevant)
  int*   out     = (int*)d_out;
  float* partial = (float*)d_ws;             // NROW*SPLIT*HW f32 = 3 MB, fully rewritten

  Perm76 perm;
  compute_perm(perm.p);                      // deterministic host compute, kernel-arg baked

  pv_conv<<<NROW * SPLIT, 512, 0, stream>>>(feat, dw_w, pw_w, partial);
  pv_select<<<NROW, 512, 0, stream>>>(partial, out, perm);
}

// Round 11
// 18.048 us; speedup vs baseline: 1.3275x; 1.1290x over previous
//
#include <hip/hip_runtime.h>
#include <cstdint>
#include <cstddef>
#include <algorithm>

// ---------------- problem constants ----------------
#define NROW 16      // only bn rows 0..15 feed the outputs (n=16)
#define CTOT 384
#define HW   1024    // 32*32
#define KSEL 20
#define PSEL 96
#define NREM 76      // P - K
#define NUNSEL 1004  // HW - K

#define CPB   8                  // channels per block (kernel A)
#define SPLIT (CTOT / CPB)       // 48

typedef unsigned long long u64;

struct Perm76 { int p[NREM]; };

// ---------------- conv job: 4x4 tile of one channel, rows in registers, halos via shfl ----------------
__device__ __forceinline__ void conv_job(const float4* f6, const float* w9,
                                         int b, int c, float acc[4][4])
{
  #pragma unroll
  for (int m = 0; m < 6; ++m) {
    float4 f = f6[m];
    const bool dead = (b == 0 && m == 0) || (b == 7 && m == 5);   // out-of-plane row
    if (dead) { f.x = 0.f; f.y = 0.f; f.z = 0.f; f.w = 0.f; }
    float L = __shfl_up(f.w, 1);     // col 4c-1 from lane-1 (row-mask inherited)
    float R = __shfl_down(f.x, 1);   // col 4c+4 from lane+1
    if (c == 0) L = 0.f;
    if (c == 7) R = 0.f;
    const float c6[6] = { L, f.x, f.y, f.z, f.w, R };
    #pragma unroll
    for (int j = 0; j < 4; ++j) {
      const int d = m - j;           // kernel row
      if (d >= 0 && d < 3) {
        #pragma unroll
        for (int k = 0; k < 4; ++k)
          acc[j][k] += c6[k]     * w9[3 * d]
                     + c6[k + 1] * w9[3 * d + 1]
                     + c6[k + 2] * w9[3 * d + 2];
      }
    }
  }
}

// ---------------- kernel A: shuffle-conv (R7-proven) -> partial planes; also zeroes tickets ----------------
// grid = NROW*SPLIT (768) blocks x 256t = 3 blocks/CU. Block (r,s): wave w does channels
// s*8+2w, s*8+2w+1. Cross-wave sum via 16 KB LDS, float4 partial store.
__global__ __launch_bounds__(256) void pv_conv(
    const float* __restrict__ feat, const float* __restrict__ dw_w,
    const float* __restrict__ pw_w, float* __restrict__ partial,
    int* __restrict__ ticket)
{
  __shared__ float red[4][HW];                  // 16 KB
  const int t = threadIdx.x;
  const int w = t >> 6, lane = t & 63;
  const int b = lane >> 3, c = lane & 7;        // 4x4 tile at rows 4b.., cols 4c..
  const int r = blockIdx.x & (NROW - 1);
  const int s = blockIdx.x >> 4;

  if (s == 0 && t == 0) ticket[r] = 0;          // visible to kernel B at kernel boundary

  const int chA = s * CPB + 2 * w;
  const float* baseA = feat + ((size_t)r * CTOT + chA) * HW;
  const float* baseB = baseA + HW;

  // issue all 12 row-loads first (coalesced float4; halo rows dedup in L1/L2)
  float4 fa[6], fb[6];
  #pragma unroll
  for (int m = 0; m < 6; ++m) {
    const int row = 4 * b + m - 1;
    const int rc = row < 0 ? 0 : (row > 31 ? 31 : row);
    fa[m] = *reinterpret_cast<const float4*>(baseA + rc * 32 + 4 * c);
  }
  #pragma unroll
  for (int m = 0; m < 6; ++m) {
    const int row = 4 * b + m - 1;
    const int rc = row < 0 ? 0 : (row > 31 ? 31 : row);
    fb[m] = *reinterpret_cast<const float4*>(baseB + rc * 32 + 4 * c);
  }

  // fused weights (wave-uniform addresses -> cached)
  float wA[9], wB[9];
  {
    const float pa = pw_w[chA], pb = pw_w[chA + 1];
    #pragma unroll
    for (int i = 0; i < 9; ++i) {
      wA[i] = dw_w[chA * 9 + i] * pa;
      wB[i] = dw_w[(chA + 1) * 9 + i] * pb;
    }
  }

  float acc[4][4];
  #pragma unroll
  for (int j = 0; j < 4; ++j)
    #pragma unroll
    for (int k = 0; k < 4; ++k) acc[j][k] = 0.f;

  conv_job(fa, wA, b, c, acc);
  conv_job(fb, wB, b, c, acc);

  // cross-wave reduction (disjoint buffers; conflict-free float4 traffic)
  #pragma unroll
  for (int j = 0; j < 4; ++j)
    *reinterpret_cast<float4*>(&red[w][(4 * b + j) * 32 + 4 * c]) =
        make_float4(acc[j][0], acc[j][1], acc[j][2], acc[j][3]);
  __syncthreads();

  float4 sum = make_float4(0.f, 0.f, 0.f, 0.f);
  #pragma unroll
  for (int g = 0; g < 4; ++g) {
    const float4 v = *reinterpret_cast<const float4*>(&red[g][4 * t]);
    sum.x += v.x; sum.y += v.y; sum.z += v.z; sum.w += v.w;
  }
  *reinterpret_cast<float4*>(partial + ((size_t)(r * SPLIT + s)) * HW + 4 * t) = sum;
}

// ---------------- kernel B: slice reduce+top20 (R7 B1) + atomic ticket + finisher select (R7 B2) ----------------
// grid = 128 blocks (8 slices per image) x 256t. Each block publishes 20 u64 keys via atomicExch;
// the 8th arriver per image (atomicAdd ticket) runs the select and emits. No fences (R5 lesson):
// producer exchanges are drained by __syncthreads' vmcnt(0) before the ticket atomic issues, and
// all transfers go through the device-coherent atomic point.
__global__ __launch_bounds__(256) void pv_reduceSelect(
    const float* __restrict__ partial, u64* __restrict__ cand,
    int* __restrict__ ticket, int* __restrict__ out, Perm76 perm)
{
  __shared__ float red[8][128];
  __shared__ u64 keysh[128];
  __shared__ u64 candL[8 * KSEL];
  __shared__ int votes[KSEL];
  __shared__ int maskv[HW];
  __shared__ int wsumS[4];
  __shared__ int unsel[NUNSEL];
  __shared__ int isFinS;

  const int r = blockIdx.x >> 3;
  const int q = blockIdx.x & 7;
  const int t = threadIdx.x;
  const int sg = t >> 5, l32 = t & 31;

  // phase 1 (R7 B1 verbatim): group sg reduces planes sg, sg+8, ..., sg+40 over the 128-px slice
  const float* bp = partial + ((size_t)(r * SPLIT + sg)) * HW + q * 128 + 4 * l32;
  float4 a = make_float4(0.f, 0.f, 0.f, 0.f);
  #pragma unroll
  for (int i = 0; i < 6; ++i) {
    const float4 v = *reinterpret_cast<const float4*>(bp + (size_t)(8 * i) * HW);
    a.x += v.x; a.y += v.y; a.z += v.z; a.w += v.w;
  }
  *reinterpret_cast<float4*>(&red[sg][4 * l32]) = a;
  __syncthreads();

  if (t < 128) {
    float sc = 0.f;
    #pragma unroll
    for (int g = 0; g < 8; ++g) sc += red[g][t];
    const uint32_t bb = __float_as_uint(sc);
    const uint32_t mm = (bb & 0x80000000u) ? ~bb : (bb | 0x80000000u);
    const int gpx = q * 128 + t;
    keysh[t] = ((u64)mm << 32) | (uint32_t)(1023 - gpx);  // larger wins; tie -> smaller idx
  }
  __syncthreads();
  if (t < 128) {
    const u64 my = keysh[t];
    int rank = 0;
    for (int j = 0; j < 128; ++j) rank += (keysh[j] > my);  // broadcast reads, unique keys
    if (rank < KSEL)
      atomicExch(&cand[((size_t)(r * 8 + q)) * KSEL + rank], my);  // device-coherent publish
  }
  __syncthreads();                     // drains vmcnt: all exchanges complete before ticket

  if (t == 0) isFinS = (atomicAdd(&ticket[r], 1) == 7);
  __syncthreads();
  if (!isFinS) return;

  // ---- finisher: R7 B2 verbatim, candidates read back via atomic reads ----
  if (t < 8 * KSEL) candL[t] = atomicAdd(&cand[(size_t)r * 8 * KSEL + t], 0ull);
  maskv[t] = 0; maskv[t + 256] = 0; maskv[t + 512] = 0; maskv[t + 768] = 0;
  __syncthreads();

  // exact global top-20 (union of slice top-20s contains it)
  if (t < 8 * KSEL) {
    const u64 my = candL[t];
    int rank = 0;
    for (int j = 0; j < 8 * KSEL; ++j) rank += (candL[j] > my);
    if (rank < KSEL) votes[rank] = 1023 - (int)(my & 1023ull);
  }
  __syncthreads();

  // selected coords + mask
  if (t < KSEL) {
    const int idx = votes[t];
    maskv[idx] = 1;
    int xx = idx & 31, yy = idx >> 5;
    if (xx < 1) xx = 1;                      // clip(.,1,31); upper bound can't trigger
    if (yy < 1) yy = 1;
    out[r * PSEL + t]               = xx;
    out[NROW * PSEL + r * PSEL + t] = yy;
  }
  __syncthreads();

  // unselected indices ascending via shfl prefix over !mask
  const int lane = t & 63, wv = t >> 6;
  int cnt = 0;
  #pragma unroll
  for (int j = 0; j < 4; ++j) cnt += (maskv[t * 4 + j] == 0);
  int inc = cnt;
  #pragma unroll
  for (int dd = 1; dd < 64; dd <<= 1) {
    const int o = __shfl_up(inc, dd);
    if (lane >= dd) inc += o;
  }
  if (lane == 63) wsumS[wv] = inc;
  __syncthreads();
  int basep = 0;
  for (int i = 0; i < 4; ++i) if (i < wv) basep += wsumS[i];
  int pos = basep + inc - cnt;               // exclusive prefix
  #pragma unroll
  for (int j = 0; j < 4; ++j) {
    const int i = t * 4 + j;
    if (!maskv[i]) unsel[pos++] = i;
  }
  __syncthreads();

  // random remaining via fixed permutation
  if (t < NREM) {
    const int u = unsel[perm.p[t]];
    int xx = u & 31, yy = u >> 5;
    if (xx < 1) xx = 1;
    if (yy < 1) yy = 1;
    out[r * PSEL + KSEL + t]               = xx;
    out[NROW * PSEL + r * PSEL + KSEL + t] = yy;
  }
}

// ---------------- host: JAX threefry2x32 (partitionable) ----------------
static inline uint32_t rotl32(uint32_t v, uint32_t n) { return (v << n) | (v >> (32 - n)); }

static void tf2x32(uint32_t k0, uint32_t k1, uint32_t x0, uint32_t x1,
                   uint32_t* o0, uint32_t* o1)
{
  const uint32_t ks[3] = { k0, k1, k0 ^ k1 ^ 0x1BD11BDAu };
  static const uint32_t rot[2][4] = { {13, 15, 26, 6}, {17, 29, 16, 24} };
  x0 += ks[0]; x1 += ks[1];
  for (int i = 0; i < 5; ++i) {
    const uint32_t* rr = rot[i & 1];
    for (int j = 0; j < 4; ++j) { x0 += x1; x1 = rotl32(x1, rr[j]); x1 ^= x0; }
    x0 += ks[(i + 1) % 3];
    x1 += ks[(i + 2) % 3] + (uint32_t)(i + 1);
  }
  *o0 = x0; *o1 = x1;
}

// perm = jax.random.permutation(jax.random.key(42), 1004)[:76]  (threefry_partitionable)
static void compute_perm(int* perm_out)
{
  uint32_t bits[NUNSEL];
  uint32_t sk0, sk1;
  { uint32_t o0, o1; tf2x32(0u, 42u, 0u, 1u, &o0, &o1); sk0 = o0; sk1 = o1; }
  for (int i = 0; i < NUNSEL; ++i) {
    uint32_t o0, o1; tf2x32(sk0, sk1, 0u, (uint32_t)i, &o0, &o1);
    bits[i] = o0 ^ o1;
  }
  int idx[NUNSEL];
  for (int i = 0; i < NUNSEL; ++i) idx[i] = i;
  std::stable_sort(idx, idx + NUNSEL, [&](int a, int b) { return bits[a] < bits[b]; });
  for (int j = 0; j < NREM; ++j) perm_out[j] = idx[j];
}

extern "C" void kernel_launch(void* const* d_in, const int* in_sizes, int n_in,
                              void* d_out, int out_size, void* d_ws, size_t ws_size,
                              hipStream_t stream)
{
  (void)in_sizes; (void)n_in; (void)out_size; (void)ws_size;
  const float* feat = (const float*)d_in[0];
  const float* dw_w = (const float*)d_in[1];
  // d_in[2] = dw_b (zeros; constant shift, ordering-irrelevant)
  const float* pw_w = (const float*)d_in[3];
  // d_in[4] = pw_b (constant shift, ordering-irrelevant)
  int*   out     = (int*)d_out;
  float* partial = (float*)d_ws;                                // 16*48*4 KB = 3 MB
  u64*   cand    = (u64*)((char*)d_ws + (size_t)NROW * SPLIT * HW * sizeof(float)); // 16*160 u64
  int*   ticket  = (int*)(cand + (size_t)NROW * 8 * KSEL);      // 16 ints, zeroed by kernel A

  Perm76 perm;
  compute_perm(perm.p);                      // deterministic host compute, kernel-arg baked

  pv_conv<<<NROW * SPLIT, 256, 0, stream>>>(feat, dw_w, pw_w, partial, ticket);
  pv_reduceSelect<<<128, 256, 0, stream>>>(partial, cand, ticket, out, perm);
}

// Round 12
// 17.707 us; speedup vs baseline: 1.3531x; 1.0193x over previous
//
#include <hip/hip_runtime.h>
#include <cstdint>
#include <cstddef>
#include <algorithm>

// ---------------- problem constants ----------------
#define NROW 16      // only bn rows 0..15 feed the outputs (n=16)
#define CTOT 384
#define HW   1024    // 32*32
#define KSEL 20
#define PSEL 96
#define NREM 76      // P - K
#define NUNSEL 1004  // HW - K

#define CPB   8                  // channels per block (kernel A)
#define SPLIT (CTOT / CPB)       // 48
#define PLW   1040               // padded LDS plane stride (floats): 4 bands * 260

typedef unsigned long long u64;

struct Perm76 { int p[NREM]; };

// ---------------- kernel A: zero-over-read shuffle-conv -> partial planes ----------------
// grid = NROW*SPLIT (768) blocks x 256t = 3 blocks/CU. Block (r,s): wave w, half h2 owns
// channel s*8+2w+h2. Lane (within 32-half) h: band b=h>>3 (rows 8b..8b+7), colgrp c=h&7
// (cols 4c..4c+3). Every feature element is loaded exactly once (halos via shfl).
__global__ __launch_bounds__(256) void pv_conv(
    const float* __restrict__ feat, const float* __restrict__ dw_w,
    const float* __restrict__ pw_w, float* __restrict__ partial,
    int* __restrict__ ticket)
{
  __shared__ float red[8 * PLW];                // 33,280 B
  const int t = threadIdx.x;
  const int w = t >> 6, lane = t & 63;
  const int h = lane & 31, hb = lane & 32;      // half-lane idx, half selector bit
  const int b = h >> 3, c = h & 7;
  const int r = blockIdx.x & (NROW - 1);
  const int s = blockIdx.x >> 4;

  if (s == 0 && t == 0) ticket[r] = 0;          // visible to kernel B at kernel boundary

  const int ch = s * CPB + 2 * w + (lane >> 5);
  const float* base = feat + ((size_t)r * CTOT + ch) * HW + 4 * c;

  // 8 own rows, each element of the plane loaded exactly once across the block
  float4 f[8];
  #pragma unroll
  for (int j = 0; j < 8; ++j)
    f[j] = *reinterpret_cast<const float4*>(base + (8 * b + j) * 32);

  // fused weights (half-wave-uniform)
  float w9[9];
  {
    const float pw = pw_w[ch];
    #pragma unroll
    for (int i = 0; i < 9; ++i) w9[i] = dw_w[ch * 9 + i] * pw;
  }

  // halo rows via shfl from lanes +-8 (band edges -> zero)
  const int sm = hb | ((h - 8) & 31), sp = hb | ((h + 8) & 31);
  float4 fm, fp;
  fm.x = __shfl(f[7].x, sm); fm.y = __shfl(f[7].y, sm);
  fm.z = __shfl(f[7].z, sm); fm.w = __shfl(f[7].w, sm);
  fp.x = __shfl(f[0].x, sp); fp.y = __shfl(f[0].y, sp);
  fp.z = __shfl(f[0].z, sp); fp.w = __shfl(f[0].w, sp);
  if (b == 0) { fm.x = 0.f; fm.y = 0.f; fm.z = 0.f; fm.w = 0.f; }
  if (b == 3) { fp.x = 0.f; fp.y = 0.f; fp.z = 0.f; fp.w = 0.f; }

  // halo cols: L[k]/R[k] for the 10-row sequence k=0..9 (row 8b-1+k)
  float L[10], R[10];
  #pragma unroll
  for (int k = 1; k <= 8; ++k) {
    L[k] = __shfl(f[k - 1].w, hb | ((h - 1) & 31));
    R[k] = __shfl(f[k - 1].x, hb | ((h + 1) & 31));
  }
  L[0] = __shfl(f[7].w, hb | ((h - 9) & 31));
  R[0] = __shfl(f[7].x, hb | ((h - 7) & 31));
  L[9] = __shfl(f[0].w, hb | ((h + 7) & 31));
  R[9] = __shfl(f[0].x, hb | ((h + 9) & 31));
  if (b == 0) { L[0] = 0.f; R[0] = 0.f; }
  if (b == 3) { L[9] = 0.f; R[9] = 0.f; }
  if (c == 0) {
    #pragma unroll
    for (int k = 0; k < 10; ++k) L[k] = 0.f;
  }
  if (c == 7) {
    #pragma unroll
    for (int k = 0; k < 10; ++k) R[k] = 0.f;
  }

  // conv: out rows j=0..7, kernel rows d=0..2 read seq row k=j+d
  float acc[8][4];
  #pragma unroll
  for (int j = 0; j < 8; ++j)
    #pragma unroll
    for (int k = 0; k < 4; ++k) acc[j][k] = 0.f;

  #pragma unroll
  for (int j = 0; j < 8; ++j) {
    #pragma unroll
    for (int d = 0; d < 3; ++d) {
      const int k = j + d;
      const float4 C = (k == 0) ? fm : (k == 9 ? fp : f[k - 1]);
      const float a0 = L[k], a1 = C.x, a2 = C.y, a3 = C.z, a4 = C.w, a5 = R[k];
      const float t0 = w9[3 * d], t1 = w9[3 * d + 1], t2 = w9[3 * d + 2];
      acc[j][0] += a0 * t0 + a1 * t1 + a2 * t2;
      acc[j][1] += a1 * t0 + a2 * t1 + a3 * t2;
      acc[j][2] += a2 * t0 + a3 * t1 + a4 * t2;
      acc[j][3] += a3 * t0 + a4 * t1 + a5 * t2;
    }
  }

  // park per-channel plane in LDS (plane 2w+h2; +4-float band padding kills 4-way conflicts)
  {
    float* pl = &red[(2 * w + (lane >> 5)) * PLW + b * 260 + 4 * c];
    #pragma unroll
    for (int j = 0; j < 8; ++j)
      *reinterpret_cast<float4*>(pl + j * 32) =
          make_float4(acc[j][0], acc[j][1], acc[j][2], acc[j][3]);
  }
  __syncthreads();

  // block reduce 8 channel planes -> partial plane (float4, coalesced)
  {
    const int row = t >> 3;
    const int off = (row >> 3) * 260 + (row & 7) * 32 + 4 * (t & 7);
    float4 sum = make_float4(0.f, 0.f, 0.f, 0.f);
    #pragma unroll
    for (int p = 0; p < 8; ++p) {
      const float4 v = *reinterpret_cast<const float4*>(&red[p * PLW + off]);
      sum.x += v.x; sum.y += v.y; sum.z += v.z; sum.w += v.w;
    }
    *reinterpret_cast<float4*>(partial + ((size_t)(r * SPLIT + s)) * HW + 4 * t) = sum;
  }
}

// ---------------- kernel B: slice reduce+top20 + atomic ticket + finisher select (R11-proven) ----------------
__global__ __launch_bounds__(256) void pv_reduceSelect(
    const float* __restrict__ partial, u64* __restrict__ cand,
    int* __restrict__ ticket, int* __restrict__ out, Perm76 perm)
{
  __shared__ float red[8][128];
  __shared__ u64 keysh[128];
  __shared__ u64 candL[8 * KSEL];
  __shared__ int votes[KSEL];
  __shared__ int maskv[HW];
  __shared__ int wsumS[4];
  __shared__ int unsel[NUNSEL];
  __shared__ int isFinS;

  const int r = blockIdx.x >> 3;
  const int q = blockIdx.x & 7;
  const int t = threadIdx.x;
  const int sg = t >> 5, l32 = t & 31;

  // group sg reduces planes sg, sg+8, ..., sg+40 over the 128-px slice
  const float* bp = partial + ((size_t)(r * SPLIT + sg)) * HW + q * 128 + 4 * l32;
  float4 a = make_float4(0.f, 0.f, 0.f, 0.f);
  #pragma unroll
  for (int i = 0; i < 6; ++i) {
    const float4 v = *reinterpret_cast<const float4*>(bp + (size_t)(8 * i) * HW);
    a.x += v.x; a.y += v.y; a.z += v.z; a.w += v.w;
  }
  *reinterpret_cast<float4*>(&red[sg][4 * l32]) = a;
  __syncthreads();

  if (t < 128) {
    float sc = 0.f;
    #pragma unroll
    for (int g = 0; g < 8; ++g) sc += red[g][t];
    const uint32_t bb = __float_as_uint(sc);
    const uint32_t mm = (bb & 0x80000000u) ? ~bb : (bb | 0x80000000u);
    const int gpx = q * 128 + t;
    keysh[t] = ((u64)mm << 32) | (uint32_t)(1023 - gpx);  // larger wins; tie -> smaller idx
  }
  __syncthreads();
  if (t < 128) {
    const u64 my = keysh[t];
    int rank = 0;
    for (int j = 0; j < 128; ++j) rank += (keysh[j] > my);  // broadcast reads, unique keys
    if (rank < KSEL)
      atomicExch(&cand[((size_t)(r * 8 + q)) * KSEL + rank], my);  // device-coherent publish
  }
  __syncthreads();                     // drains vmcnt: all exchanges complete before ticket

  if (t == 0) isFinS = (atomicAdd(&ticket[r], 1) == 7);
  __syncthreads();
  if (!isFinS) return;

  // ---- finisher: global top-20 from 160 candidates, selection, emit ----
  if (t < 8 * KSEL) candL[t] = atomicAdd(&cand[(size_t)r * 8 * KSEL + t], 0ull);
  maskv[t] = 0; maskv[t + 256] = 0; maskv[t + 512] = 0; maskv[t + 768] = 0;
  __syncthreads();

  if (t < 8 * KSEL) {
    const u64 my = candL[t];
    int rank = 0;
    for (int j = 0; j < 8 * KSEL; ++j) rank += (candL[j] > my);
    if (rank < KSEL) votes[rank] = 1023 - (int)(my & 1023ull);
  }
  __syncthreads();

  if (t < KSEL) {
    const int idx = votes[t];
    maskv[idx] = 1;
    int xx = idx & 31, yy = idx >> 5;
    if (xx < 1) xx = 1;                      // clip(.,1,31); upper bound can't trigger
    if (yy < 1) yy = 1;
    out[r * PSEL + t]               = xx;
    out[NROW * PSEL + r * PSEL + t] = yy;
  }
  __syncthreads();

  const int lane = t & 63, wv = t >> 6;
  int cnt = 0;
  #pragma unroll
  for (int j = 0; j < 4; ++j) cnt += (maskv[t * 4 + j] == 0);
  int inc = cnt;
  #pragma unroll
  for (int dd = 1; dd < 64; dd <<= 1) {
    const int o = __shfl_up(inc, dd);
    if (lane >= dd) inc += o;
  }
  if (lane == 63) wsumS[wv] = inc;
  __syncthreads();
  int basep = 0;
  for (int i = 0; i < 4; ++i) if (i < wv) basep += wsumS[i];
  int pos = basep + inc - cnt;               // exclusive prefix
  #pragma unroll
  for (int j = 0; j < 4; ++j) {
    const int i = t * 4 + j;
    if (!maskv[i]) unsel[pos++] = i;
  }
  __syncthreads();

  if (t < NREM) {
    const int u = unsel[perm.p[t]];
    int xx = u & 31, yy = u >> 5;
    if (xx < 1) xx = 1;
    if (yy < 1) yy = 1;
    out[r * PSEL + KSEL + t]               = xx;
    out[NROW * PSEL + r * PSEL + KSEL + t] = yy;
  }
}

// ---------------- host: JAX threefry2x32 (partitionable) ----------------
static inline uint32_t rotl32(uint32_t v, uint32_t n) { return (v << n) | (v >> (32 - n)); }

static void tf2x32(uint32_t k0, uint32_t k1, uint32_t x0, uint32_t x1,
                   uint32_t* o0, uint32_t* o1)
{
  const uint32_t ks[3] = { k0, k1, k0 ^ k1 ^ 0x1BD11BDAu };
  static const uint32_t rot[2][4] = { {13, 15, 26, 6}, {17, 29, 16, 24} };
  x0 += ks[0]; x1 += ks[1];
  for (int i = 0; i < 5; ++i) {
    const uint32_t* rr = rot[i & 1];
    for (int j = 0; j < 4; ++j) { x0 += x1; x1 = rotl32(x1, rr[j]); x1 ^= x0; }
    x0 += ks[(i + 1) % 3];
    x1 += ks[(i + 2) % 3] + (uint32_t)(i + 1);
  }
  *o0 = x0; *o1 = x1;
}

// perm = jax.random.permutation(jax.random.key(42), 1004)[:76]  (threefry_partitionable)
static void compute_perm(int* perm_out)
{
  uint32_t bits[NUNSEL];
  uint32_t sk0, sk1;
  { uint32_t o0, o1; tf2x32(0u, 42u, 0u, 1u, &o0, &o1); sk0 = o0; sk1 = o1; }
  for (int i = 0; i < NUNSEL; ++i) {
    uint32_t o0, o1; tf2x32(sk0, sk1, 0u, (uint32_t)i, &o0, &o1);
    bits[i] = o0 ^ o1;
  }
  int idx[NUNSEL];
  for (int i = 0; i < NUNSEL; ++i) idx[i] = i;
  std::stable_sort(idx, idx + NUNSEL, [&](int a, int b) { return bits[a] < bits[b]; });
  for (int j = 0; j < NREM; ++j) perm_out[j] = idx[j];
}

extern "C" void kernel_launch(void* const* d_in, const int* in_sizes, int n_in,
                              void* d_out, int out_size, void* d_ws, size_t ws_size,
                              hipStream_t stream)
{
  (void)in_sizes; (void)n_in; (void)out_size; (void)ws_size;
  const float* feat = (const float*)d_in[0];
  const float* dw_w = (const float*)d_in[1];
  // d_in[2] = dw_b (zeros; constant shift, ordering-irrelevant)
  const float* pw_w = (const float*)d_in[3];
  // d_in[4] = pw_b (constant shift, ordering-irrelevant)
  int*   out     = (int*)d_out;
  float* partial = (float*)d_ws;                                // 16*48*4 KB = 3 MB
  u64*   cand    = (u64*)((char*)d_ws + (size_t)NROW * SPLIT * HW * sizeof(float)); // 16*160 u64
  int*   ticket  = (int*)(cand + (size_t)NROW * 8 * KSEL);      // 16 ints, zeroed by kernel A

  Perm76 perm;
  compute_perm(perm.p);                      // deterministic host compute, kernel-arg baked

  pv_conv<<<NROW * SPLIT, 256, 0, stream>>>(feat, dw_w, pw_w, partial, ticket);
  pv_reduceSelect<<<128, 256, 0, stream>>>(partial, cand, ticket, out, perm);
}